// Round 9
// baseline (41.810 us; speedup 1.0000x reference)
//
#include <hip/hip_runtime.h>

// Grayscale morphological dilation, 7x7 additive SE, zero 'same' padding:
//   out[p, i, j] = max_{a,b in 0..6} ( xz(p, i+a-3, j+b-3) + w[a,b] )
//
// R9: packed-f32 adds. CDNA4 has v_pk_add_f32 (no packed f32 max), so the
// 49 adds/output are packed pairwise over tap index b: candidates (b,b+1)
// use adjacent input cols AND adjacent weights -> natural v2f pairs.
// Per output per SE-row: 3 pk_add + 1 add + 3 v_max3 + 1 max.
// Even pairs come free from the float4 loads (e[k] = rv[2k:2k+1]);
// odd pairs o[k] = {rv[2k+1], rv[2k+2]} built once per row, shared by all
// 7 output rows. Structure otherwise = R7/R8 (40us): 4x8 thread tile,
// 256x32 block tile, grid (2,16,64), wave-uniform scalar row base,
// SGPR weights, 1-deep prefetch, literal indices only.
// Also fixes latent bug: row-OOB zero reads now stay inside ZROW
// (ZROW[272], zrb offset by -colbase) instead of reading past a 16-float
// array (R7/R8 passed only because trailing BSS happened to be zero).

#define HH 512
#define WW 512

typedef float v2f __attribute__((ext_vector_type(2)));

__device__ __align__(16) const float ZROW[272] = {};  // zero region

__device__ __forceinline__ float max3f(float a, float b, float c) {
  float d;
  asm("v_max3_f32 %0, %1, %2, %3" : "=v"(d) : "v"(a), "v"(b), "v"(c));
  return d;
}

#define LOADROW(E, K)                                                        \
  {                                                                          \
    const int r_ = row0 - 3 + (K);              /* scalar */                 \
    const float* rb_ = ((unsigned)r_ < (unsigned)HH)                         \
                           ? (xp + (ptrdiff_t)r_ * WW)                       \
                           : zrb;               /* s_cselect_b64 */          \
    const float* p0_ = okL ? rb_ + col0 - 4 : &ZROW[0];                      \
    const float* p2_ = okR ? rb_ + col0 + 4 : &ZROW[0];                      \
    float4 v0_ = *reinterpret_cast<const float4*>(p0_);                      \
    float4 v1_ = *reinterpret_cast<const float4*>(rb_ + col0);               \
    float4 v2_ = *reinterpret_cast<const float4*>(p2_);                      \
    E[0] = (v2f){v0_.x, v0_.y};  E[1] = (v2f){v0_.z, v0_.w};                 \
    E[2] = (v2f){v1_.x, v1_.y};  E[3] = (v2f){v1_.z, v1_.w};                 \
    E[4] = (v2f){v2_.x, v2_.y};  E[5] = (v2f){v2_.z, v2_.w};                 \
  }

// Output j uses input cols rv[j+1 .. j+7] (rv[k] = col col0+k-4).
// Tap pairs (b,b+1) at pair-bases j+1, j+3, j+5; scalar tail rv[j+7].
//   j=0: o0,o1,o2, e3.y   j=1: e1,e2,e3, e4.x
//   j=2: o1,o2,o3, e4.y   j=3: e2,e3,e4, e5.x
#define ONEOUT(T, K, J, P1, P2, P3, S)                                       \
  {                                                                          \
    const int a_ = (K) - (T);                                                \
    const v2f c01_ = (P1) + w2[a_][0];          /* v_pk_add_f32 */           \
    const v2f c23_ = (P2) + w2[a_][1];                                       \
    const v2f c45_ = (P3) + w2[a_][2];                                       \
    const float c6_ = (S) + w6[a_];                                          \
    const float t1_ = max3f(c01_.x, c01_.y, c23_.x);                         \
    const float t2_ = max3f(c23_.y, c45_.x, c45_.y);                         \
    acc[T][J] = ((K) == (T))                                                 \
                    ? max3f(t1_, t2_, c6_)               /* first touch */   \
                    : max3f(t1_, t2_, fmaxf(c6_, acc[T][J]));                \
  }

// K literal at every expansion site; all indices fold at compile time.
#define COMPROW(E, K)                                                        \
  {                                                                          \
    const v2f o0_ = (v2f){E[0].y, E[1].x};                                   \
    const v2f o1_ = (v2f){E[1].y, E[2].x};                                   \
    const v2f o2_ = (v2f){E[2].y, E[3].x};                                   \
    const v2f o3_ = (v2f){E[3].y, E[4].x};                                   \
    _Pragma("unroll") for (int t = 0; t < 8; ++t) {                          \
      if (t <= (K) && t + 6 >= (K)) {                                        \
        ONEOUT(t, K, 0, o0_, o1_, o2_, E[3].y);                              \
        ONEOUT(t, K, 1, E[1], E[2], E[3], E[4].x);                           \
        ONEOUT(t, K, 2, o1_, o2_, o3_, E[4].y);                              \
        ONEOUT(t, K, 3, E[2], E[3], E[4], E[5].x);                           \
      }                                                                      \
    }                                                                        \
  }

#define STOREROW(T)                                                          \
  {                                                                          \
    float* orow_ = op + (ptrdiff_t)(row0 + (T)) * WW + col0;                 \
    *reinterpret_cast<float4*>(orow_) =                                      \
        make_float4(acc[T][0], acc[T][1], acc[T][2], acc[T][3]);             \
  }

__global__ __launch_bounds__(256) void dilate7(const float* __restrict__ x,
                                               const float* __restrict__ wg,
                                               float* __restrict__ out) {
  const int tid = threadIdx.x;
  const int lc = tid & 63;                          // 64 thread-cols per wave
  const int colbase = blockIdx.x * 256;             // scalar
  const int col0 = colbase + lc * 4;                // output col base (mult 4)
  // tid>>6 is the wave id -> row0 is wave-uniform; force it scalar.
  const int row0 =
      __builtin_amdgcn_readfirstlane(blockIdx.y * 32 + (tid >> 6) * 8);

  const size_t plane_off = (size_t)blockIdx.z * (size_t)(HH * WW);
  const float* xp = x + plane_off;
  float* op = out + plane_off;

  // Weights -> SGPRs (uniform loads), then pack pairs (w[a][2p], w[a][2p+1]).
  float wv[49];
#pragma unroll
  for (int i = 0; i < 49; ++i)
    wv[i] = __int_as_float(__builtin_amdgcn_readfirstlane(__float_as_int(wg[i])));
  v2f w2[7][3];
  float w6[7];
#pragma unroll
  for (int a = 0; a < 7; ++a) {
    w2[a][0] = (v2f){wv[7 * a + 0], wv[7 * a + 1]};
    w2[a][1] = (v2f){wv[7 * a + 2], wv[7 * a + 3]};
    w2[a][2] = (v2f){wv[7 * a + 4], wv[7 * a + 5]};
    w6[a] = wv[7 * a + 6];
  }

  // Row base when the row is OOB: offset so rb_+col0-4 .. rb_+col0+7 all
  // land inside ZROW for every lane of this block (local col0 in [0,252]).
  const float* zrb = ZROW + 4 - colbase;
  const bool okL = (col0 >= 4);        // false only for global col0 == 0
  const bool okR = (col0 + 8 <= WW);   // false only for global col0 == 508

  float acc[8][4];                     // first write at K==t, no init needed
  v2f eA[6], eB[6];

  // 1-deep pipeline: load row K+1 while computing row K.
  LOADROW(eA, 0);
  LOADROW(eB, 1);   COMPROW(eA, 0);
  LOADROW(eA, 2);   COMPROW(eB, 1);
  LOADROW(eB, 3);   COMPROW(eA, 2);
  LOADROW(eA, 4);   COMPROW(eB, 3);
  LOADROW(eB, 5);   COMPROW(eA, 4);
  LOADROW(eA, 6);   COMPROW(eB, 5);
  LOADROW(eB, 7);   COMPROW(eA, 6);   STOREROW(0);
  LOADROW(eA, 8);   COMPROW(eB, 7);   STOREROW(1);
  LOADROW(eB, 9);   COMPROW(eA, 8);   STOREROW(2);
  LOADROW(eA, 10);  COMPROW(eB, 9);   STOREROW(3);
  LOADROW(eB, 11);  COMPROW(eA, 10);  STOREROW(4);
  LOADROW(eA, 12);  COMPROW(eB, 11);  STOREROW(5);
  LOADROW(eB, 13);  COMPROW(eA, 12);  STOREROW(6);
  COMPROW(eB, 13);  STOREROW(7);
}

extern "C" void kernel_launch(void* const* d_in, const int* in_sizes, int n_in,
                              void* d_out, int out_size, void* d_ws, size_t ws_size,
                              hipStream_t stream) {
  const float* x = (const float*)d_in[0];
  const float* w = (const float*)d_in[1];
  float* out = (float*)d_out;
  const int planes = in_sizes[0] / (HH * WW);   // 8*8 = 64
  dim3 grid(2, 16, planes);                     // 256x32 tile -> exact cover
  dilate7<<<grid, dim3(256, 1, 1), 0, stream>>>(x, w, out);
}